// Round 3
// baseline (255.758 us; speedup 1.0000x reference)
//
#include <hip/hip_runtime.h>

// Problem constants (fixed by the reference)
static constexpr int kB = 2;
static constexpr int kNV = 30000;
static constexpr int kD = 8;    // NDIRS
static constexpr int kR = 3;    // NRINGS
static constexpr int kC = 16;   // C
static constexpr int kF = 16;   // NF

typedef float v2f __attribute__((ext_vector_type(2)));

// One thread per (vertex, d). 8 consecutive lanes share a vertex.
// Each lane gathers ONLY its own ring entries (12 float4 loads) and the
// circular rotation is done with __shfl of the register-resident patch data
// (ds_bpermute, LDS pipe) instead of re-loading from memory 8x.
__global__ __launch_bounds__(256) void sgc_kernel(
    const float* __restrict__ y,          // (B, NV, NDIRS, C)
    const int*   __restrict__ sync_field, // (B, NV, NRINGS, NDIRS, 3)
    const float* __restrict__ kern,       // (NRINGS, NDIRS, C, NF)
    const float* __restrict__ ck,         // (C, NF)
    const float* __restrict__ bias,       // (NF,)
    float*       __restrict__ out)        // (B, NV, NF)
{
    const int t    = blockIdx.x * blockDim.x + threadIdx.x;
    const int d    = t & 7;       // this lane's direction
    const int bv   = t >> 3;      // flattened (b, v), 0..59999
    const int grpBase = (threadIdx.x & 63) & 56;  // first lane of 8-lane group

    // --- Gather: lane d loads ring entries (bv, r, d) only — once. ---
    float p[kR][kC];
#pragma unroll
    for (int r = 0; r < kR; ++r) {
        const int* sf = sync_field + ((size_t)(bv * kR + r) * kD + d) * 3;
        const int bi = sf[0];
        const int vi = sf[1];
        const int di = sf[2];
        const int ofs = ((bi * kNV + vi) * kD + di) * kC;
        const float4* p4 = reinterpret_cast<const float4*>(y + ofs);
#pragma unroll
        for (int i = 0; i < 4; ++i) {
            const float4 q = p4[i];
            p[r][4 * i + 0] = q.x;
            p[r][4 * i + 1] = q.y;
            p[r][4 * i + 2] = q.z;
            p[r][4 * i + 3] = q.w;
        }
    }

    // Center row y[b,v,d,:] (contiguous, own data).
    float yc[kC];
    {
        const float4* p4 =
            reinterpret_cast<const float4*>(y + (size_t)(bv * kD + d) * kC);
#pragma unroll
        for (int i = 0; i < 4; ++i) {
            const float4 q = p4[i];
            yc[4 * i + 0] = q.x;
            yc[4 * i + 1] = q.y;
            yc[4 * i + 2] = q.z;
            yc[4 * i + 3] = q.w;
        }
    }

    // Accumulators: 16 fp32 as 8 packed float2.
    v2f acc[kF / 2];
#pragma unroll
    for (int j = 0; j < kF / 2; ++j) {
        acc[j].x = bias[2 * j];
        acc[j].y = bias[2 * j + 1];
    }

    // --- Conv: out[d,f] += sum_{r,dd,c} P[r,(d+dd)&7,c] * K[r,dd,c,f] ---
    // P[r,(d+dd)&7,c] lives in lane grpBase|((d+dd)&7)'s registers -> shuffle.
#pragma unroll
    for (int dd = 0; dd < kD; ++dd) {
        const int src = grpBase | ((d + dd) & 7);   // one addr reg per dd
#pragma unroll
        for (int r = 0; r < kR; ++r) {
            const v2f* kr = reinterpret_cast<const v2f*>(
                kern + (size_t)(r * kD + dd) * kC * kF);
#pragma unroll
            for (int c = 0; c < kC; ++c) {
                const float v = __shfl(p[r][c], src, 64);
                const v2f pv = { v, v };
#pragma unroll
                for (int j = 0; j < kF / 2; ++j)
                    acc[j] += pv * kr[c * (kF / 2) + j];
            }
        }
    }

    // --- Center term: y[b,v,d,:] @ center_kernel ---
    {
        const v2f* kr = reinterpret_cast<const v2f*>(ck);
#pragma unroll
        for (int c = 0; c < kC; ++c) {
            const v2f pv = { yc[c], yc[c] };
#pragma unroll
            for (int j = 0; j < kF / 2; ++j)
                acc[j] += pv * kr[c * (kF / 2) + j];
        }
    }

    // --- ReLU, then max over the 8 directions (in-wave group reduction) ---
    float res[kF];
#pragma unroll
    for (int j = 0; j < kF / 2; ++j) {
        res[2 * j]     = fmaxf(acc[j].x, 0.0f);
        res[2 * j + 1] = fmaxf(acc[j].y, 0.0f);
    }
#pragma unroll
    for (int m = 1; m < 8; m <<= 1) {
#pragma unroll
        for (int f = 0; f < kF; ++f)
            res[f] = fmaxf(res[f], __shfl_xor(res[f], m, 64));
    }

    if (d == 0) {
        float4* o4 = reinterpret_cast<float4*>(out + (size_t)bv * kF);
#pragma unroll
        for (int i = 0; i < 4; ++i) {
            float4 v;
            v.x = res[4 * i + 0];
            v.y = res[4 * i + 1];
            v.z = res[4 * i + 2];
            v.w = res[4 * i + 3];
            o4[i] = v;
        }
    }
}

extern "C" void kernel_launch(void* const* d_in, const int* in_sizes, int n_in,
                              void* d_out, int out_size, void* d_ws, size_t ws_size,
                              hipStream_t stream) {
    const float* y    = reinterpret_cast<const float*>(d_in[0]);
    const int*   sf   = reinterpret_cast<const int*>(d_in[1]);
    const float* kern = reinterpret_cast<const float*>(d_in[2]);
    const float* ck   = reinterpret_cast<const float*>(d_in[3]);
    const float* bias = reinterpret_cast<const float*>(d_in[4]);
    float* out = reinterpret_cast<float*>(d_out);

    const int total = kB * kNV * kD;  // 480000 threads, 8 per vertex
    const int block = 256;
    const int grid  = total / block;  // 1875, exact (no tail)
    sgc_kernel<<<grid, block, 0, stream>>>(y, sf, kern, ck, bias, out);
}

// Round 4
// 178.002 us; speedup vs baseline: 1.4368x; 1.4368x over previous
//
#include <hip/hip_runtime.h>

// Problem constants (fixed by the reference)
static constexpr int kB = 2;
static constexpr int kNV = 30000;
static constexpr int kD = 8;    // NDIRS
static constexpr int kR = 3;    // NRINGS
static constexpr int kC = 16;   // C
static constexpr int kF = 16;   // NF

static constexpr int VPB = 16;  // vertices per block (block = VPB*8 = 128 thr)

// LDS layout (float words): patch[v][r][dir][c]
//   dir row padded 16 -> 20 words, vertex padded +4 words.
//   bank(read, b128 i-th quad) = 4*((tv + 5*rd) mod 8) + i*4+j  -> uniform
//   8 words/bank across the wave = the conflict-free b128 floor.
static constexpr int DIR_STRIDE  = 20;                    // words
static constexpr int RING_STRIDE = kD * DIR_STRIDE;       // 160
static constexpr int VTX_STRIDE  = kR * RING_STRIDE + 4;  // 484
static constexpr int LDS_WORDS   = VPB * VTX_STRIDE;      // 7744 (31 KB)

typedef float v2f __attribute__((ext_vector_type(2)));

__global__ __launch_bounds__(128) void sgc_kernel(
    const float* __restrict__ y,          // (B, NV, NDIRS, C)
    const int*   __restrict__ sync_field, // (B, NV, NRINGS, NDIRS, 3)
    const float* __restrict__ kern,       // (NRINGS, NDIRS, C, NF)
    const float* __restrict__ ck,         // (C, NF)
    const float* __restrict__ bias,       // (NF,)
    float*       __restrict__ out)        // (B, NV, NF)
{
    __shared__ float lds[LDS_WORDS];

    const int tid = threadIdx.x;
    const int d   = tid & 7;          // this thread's direction slot
    const int tv  = tid >> 3;         // local vertex 0..15
    const int bv  = blockIdx.x * VPB + tv;   // flattened (b,v), 0..59999

    // ---------------- Phase 1: gather -> LDS (each entry loaded ONCE) -----
    // Thread (tv,d) fetches ring entries (bv, r, d) and stores to its slot.
#pragma unroll
    for (int r = 0; r < kR; ++r) {
        const int* sf = sync_field + ((size_t)(bv * kR + r) * kD + d) * 3;
        const int bi = sf[0];
        const int vi = sf[1];
        const int di = sf[2];
        const int ofs = ((bi * kNV + vi) * kD + di) * kC;
        const float4* p4 = reinterpret_cast<const float4*>(y + ofs);
        float4* l4 = reinterpret_cast<float4*>(
            &lds[tv * VTX_STRIDE + r * RING_STRIDE + d * DIR_STRIDE]);
#pragma unroll
        for (int i = 0; i < 4; ++i) l4[i] = p4[i];  // 4x ds_write_b128
    }

    // ---------------- Center term + bias (independent of LDS; overlaps) ---
    v2f acc[kF / 2];
#pragma unroll
    for (int j = 0; j < kF / 2; ++j) {
        acc[j].x = bias[2 * j];
        acc[j].y = bias[2 * j + 1];
    }
    {
        // y[b,v,d,:] — 128 threads read 8 KB contiguous -> fully coalesced.
        float4 q[4];
        const float4* p4 =
            reinterpret_cast<const float4*>(y + (size_t)(bv * kD + d) * kC);
#pragma unroll
        for (int i = 0; i < 4; ++i) q[i] = p4[i];
        const float* pc = reinterpret_cast<const float*>(q);
        const v2f* kr = reinterpret_cast<const v2f*>(ck);
#pragma unroll
        for (int c = 0; c < kC; ++c) {
            const v2f pv = { pc[c], pc[c] };
#pragma unroll
            for (int j = 0; j < kF / 2; ++j)
                acc[j] += pv * kr[c * (kF / 2) + j];
        }
    }

    __syncthreads();

    // ---------------- Phase 2: rotated conv from LDS ----------------------
    // out[d,f] += sum_{r,dd,c} patch[v][r][(d+dd)&7][c] * K[r][dd][c][f]
    for (int dd = 0; dd < kD; ++dd) {
        const int rd = (d + dd) & 7;
        // 12 independent ds_read_b128 up front
        float4 q[kR][4];
#pragma unroll
        for (int r = 0; r < kR; ++r) {
            const float4* l4 = reinterpret_cast<const float4*>(
                &lds[tv * VTX_STRIDE + r * RING_STRIDE + rd * DIR_STRIDE]);
#pragma unroll
            for (int i = 0; i < 4; ++i) q[r][i] = l4[i];
        }
#pragma unroll
        for (int r = 0; r < kR; ++r) {
            const float* pc = reinterpret_cast<const float*>(q[r]);
            const v2f* kr = reinterpret_cast<const v2f*>(
                kern + (size_t)(r * kD + dd) * kC * kF);
#pragma unroll
            for (int c = 0; c < kC; ++c) {
                const v2f pv = { pc[c], pc[c] };
#pragma unroll
                for (int j = 0; j < kF / 2; ++j)
                    acc[j] += pv * kr[c * (kF / 2) + j];
            }
        }
    }

    // ---------------- ReLU + max over 8 directions ------------------------
    float res[kF];
#pragma unroll
    for (int j = 0; j < kF / 2; ++j) {
        res[2 * j]     = fmaxf(acc[j].x, 0.0f);
        res[2 * j + 1] = fmaxf(acc[j].y, 0.0f);
    }
#pragma unroll
    for (int m = 1; m < 8; m <<= 1) {
#pragma unroll
        for (int f = 0; f < kF; ++f)
            res[f] = fmaxf(res[f], __shfl_xor(res[f], m, 64));
    }

    if (d == 0) {
        float4* o4 = reinterpret_cast<float4*>(out + (size_t)bv * kF);
#pragma unroll
        for (int i = 0; i < 4; ++i) {
            float4 v;
            v.x = res[4 * i + 0];
            v.y = res[4 * i + 1];
            v.z = res[4 * i + 2];
            v.w = res[4 * i + 3];
            o4[i] = v;
        }
    }
}

extern "C" void kernel_launch(void* const* d_in, const int* in_sizes, int n_in,
                              void* d_out, int out_size, void* d_ws, size_t ws_size,
                              hipStream_t stream) {
    const float* y    = reinterpret_cast<const float*>(d_in[0]);
    const int*   sf   = reinterpret_cast<const int*>(d_in[1]);
    const float* kern = reinterpret_cast<const float*>(d_in[2]);
    const float* ck   = reinterpret_cast<const float*>(d_in[3]);
    const float* bias = reinterpret_cast<const float*>(d_in[4]);
    float* out = reinterpret_cast<float*>(d_out);

    const int nBlocks = (kB * kNV) / VPB;  // 3750, exact
    sgc_kernel<<<nBlocks, VPB * kD, 0, stream>>>(y, sf, kern, ck, bias, out);
}

// Round 5
// 113.152 us; speedup vs baseline: 2.2603x; 1.5731x over previous
//
#include <hip/hip_runtime.h>

// Problem constants (fixed by the reference)
static constexpr int kB = 2;
static constexpr int kNV = 30000;
static constexpr int kD = 8;    // NDIRS
static constexpr int kR = 3;    // NRINGS
static constexpr int kC = 16;   // C
static constexpr int kF = 16;   // NF
static constexpr int NP = (kB * kNV) / 2;   // 30000 vertex-pairs
static constexpr int NWAVES = 3840;         // grid: 3840 single-wave blocks

typedef short short8  __attribute__((ext_vector_type(8)));   // 8 bf16 (4 VGPRs)
typedef float floatx4 __attribute__((ext_vector_type(4)));   // MFMA acc

// Per-block (single wave) LDS layout, bytes:
//   [0,1536)    patch buf0: 48 entries (vtx,r,dir) x 16 bf16 (32 B each)
//   [1536,3072) patch buf1
//   [3072,4096) center buf0: 16 slots (vtx,d) x 64 B (c0..15 bf16 + 32 B zeros)
//   [4096,5120) center buf1
static constexpr int PATCH0   = 0;
static constexpr int PATCH_SZ = 1536;
static constexpr int CENT0    = 3072;
static constexpr int CENT_SZ  = 1024;

__device__ __forceinline__ unsigned bf16rne(float x) {
    unsigned u = __float_as_uint(x);
    return (u + 0x7fffu + ((u >> 16) & 1u)) >> 16;   // round-to-nearest-even
}

// K-dim mapping: k = dd*48 + r*16 + c  (conv, k<384); k=384+c center; 400..415 zero.
// Chunk kk (0..11), quad q: g = kk*4+q, k_base = 8g -> dd=g/6, r=(g%6)>>1, ch=g&1.

__global__ __launch_bounds__(64) void sgc_kernel(
    const float* __restrict__ y,          // (B, NV, NDIRS, C)
    const int*   __restrict__ sync_field, // (B, NV, NRINGS, NDIRS, 3)
    const float* __restrict__ kern,       // (NRINGS, NDIRS, C, NF)
    const float* __restrict__ ck,         // (C, NF)
    const float* __restrict__ bias,       // (NF,)
    float*       __restrict__ out)        // (B, NV, NF)
{
    __shared__ __align__(16) char smem[PATCH_SZ * 2 + CENT_SZ * 2];

    const int lane = threadIdx.x;        // single wave: 0..63
    const int wid  = blockIdx.x;
    const int f    = lane & 15;          // MFMA col (output feature)
    const int q    = lane >> 4;          // MFMA k-block quad
    const int mvtx = (lane >> 3) & 1;    // A-row vertex-in-pair
    const int md   = lane & 7;           // A-row direction

    // ---- one-time: zero the upper 32 B of every center slot (both bufs) ----
    {
        const int zofs = CENT0 + (lane >> 5) * CENT_SZ + ((lane >> 1) & 15) * 64
                         + 32 + (lane & 1) * 16;
        *(uint4*)(smem + zofs) = make_uint4(0u, 0u, 0u, 0u);
    }

    // ---- per-lane chunk geometry + B-fragments (once per wave) ----
    int aOfs[12];
    short8 bfrag[13];
#pragma unroll
    for (int kk = 0; kk < 12; ++kk) {
        const int g   = kk * 4 + q;
        const int dd  = (g * 43) >> 8;       // g/6 for g<48
        const int rem = g - dd * 6;
        const int r   = rem >> 1;
        const int ch  = rem & 1;
        const int rot = (md + dd) & 7;
        aOfs[kk] = ((mvtx * 3 + r) * 8 + rot) * 32 + ch * 16;   // bytes in patch buf
        const int be = ((r * 8 + dd) * 16 + ch * 8) * 16 + f;   // kern elem base
        union { unsigned u[4]; short8 v; } t;
#pragma unroll
        for (int j = 0; j < 4; ++j) {
            const float a = kern[be + (2 * j) * 16];
            const float b = kern[be + (2 * j + 1) * 16];
            t.u[j] = bf16rne(a) | (bf16rne(b) << 16);
        }
        bfrag[kk] = t.v;
    }
    {   // center chunk (kk=12): q=0 -> ck c0-7, q=1 -> c8-15, q>=2 -> zeros
        union { unsigned u[4]; short8 v; } t;
        if (q < 2) {
#pragma unroll
            for (int j = 0; j < 4; ++j) {
                const float a = ck[(q * 8 + 2 * j) * 16 + f];
                const float b = ck[(q * 8 + 2 * j + 1) * 16 + f];
                t.u[j] = bf16rne(a) | (bf16rne(b) << 16);
            }
        } else {
            t.u[0] = t.u[1] = t.u[2] = t.u[3] = 0u;
        }
        bfrag[12] = t.v;
    }
    const int cOfs = (mvtx * 8 + md) * 64 + q * 16;  // q>=2 lands in zero pad
    const float biasv = bias[f];

    // ---- gather-lane roles ----
    const bool isPatch = lane < 48;
    int gvtx, gr, gdir;
    if (isPatch) {
        gvtx = (lane >= 24) ? 1 : 0;
        const int rem = lane - gvtx * 24;
        gr   = rem >> 3;
        gdir = rem & 7;
    } else {
        gvtx = (lane >> 3) & 1;
        gr   = 0;
        gdir = lane & 7;
    }
    const int wofs0  = isPatch ? (PATCH0 + ((gvtx * 3 + gr) * 8 + gdir) * 32)
                               : (CENT0 + (gvtx * 8 + gdir) * 64);
    const int wdelta = isPatch ? PATCH_SZ : CENT_SZ;

    // ---- software pipeline: gather(p) in flight, sf(p+stride) in regs ----
    float4 g0, g1, g2, g3;
    int sB0 = 0, sB1 = 0, sB2 = 0;
    int p = wid;
    if (p < NP) {
        int go;
        if (isPatch) {
            const int* s = sync_field + (((2 * p + gvtx) * 3 + gr) * 8 + gdir) * 3;
            const int a0 = s[0], a1 = s[1], a2 = s[2];
            go = ((a0 * kNV + a1) * kD + a2) * kC;
        } else {
            go = ((2 * p + gvtx) * kD + gdir) * kC;
        }
        const float4* yp = reinterpret_cast<const float4*>(y + go);
        g0 = yp[0]; g1 = yp[1]; g2 = yp[2]; g3 = yp[3];
        if (p + NWAVES < NP && isPatch) {
            const int* s = sync_field
                + (((2 * (p + NWAVES) + gvtx) * 3 + gr) * 8 + gdir) * 3;
            sB0 = s[0]; sB1 = s[1]; sB2 = s[2];
        }
    }

    int ib = 0;
    while (p < NP) {
        const int pb = PATCH0 + ib * PATCH_SZ;
        const int cb = CENT0 + ib * CENT_SZ;

        // 1. convert gather(p) -> bf16, stage to LDS buf ib
        {
            unsigned wu[8];
            const float4 gg[4] = { g0, g1, g2, g3 };
#pragma unroll
            for (int i = 0; i < 4; ++i) {
                wu[2 * i]     = bf16rne(gg[i].x) | (bf16rne(gg[i].y) << 16);
                wu[2 * i + 1] = bf16rne(gg[i].z) | (bf16rne(gg[i].w) << 16);
            }
            const int wofs = wofs0 + ib * wdelta;
            *(uint4*)(smem + wofs)      = make_uint4(wu[0], wu[1], wu[2], wu[3]);
            *(uint4*)(smem + wofs + 16) = make_uint4(wu[4], wu[5], wu[6], wu[7]);
        }

        // 2. prefetch gather(p+stride); refill sf two ahead
        const int pn = p + NWAVES;
        if (pn < NP) {
            int go;
            if (isPatch) go = ((sB0 * kNV + sB1) * kD + sB2) * kC;
            else         go = ((2 * pn + gvtx) * kD + gdir) * kC;
            const float4* yp = reinterpret_cast<const float4*>(y + go);
            g0 = yp[0]; g1 = yp[1]; g2 = yp[2]; g3 = yp[3];
            const int pnn = pn + NWAVES;
            if (pnn < NP && isPatch) {
                const int* s = sync_field
                    + (((2 * pnn + gvtx) * 3 + gr) * 8 + gdir) * 3;
                sB0 = s[0]; sB1 = s[1]; sB2 = s[2];
            }
        }

        // 3. order LDS writes before reads: compiler fence + lgkm drain.
        //    (single-wave block; per-wave LDS ops are processed in order,
        //     the waitcnt covers write completion; no s_barrier -> the
        //     prefetched global loads above stay in flight.)
        __asm__ __volatile__("" ::: "memory");
        __builtin_amdgcn_s_waitcnt(0xC07F);   // lgkmcnt(0) only
        __asm__ __volatile__("" ::: "memory");

        // 4. 13x MFMA: D[16x16] = A[16x416] * B[416x16] (+bias init)
        floatx4 acc = { biasv, biasv, biasv, biasv };
#pragma unroll
        for (int kk = 0; kk < 12; ++kk) {
            const short8 af = *(const short8*)(smem + pb + aOfs[kk]);
            acc = __builtin_amdgcn_mfma_f32_16x16x32_bf16(af, bfrag[kk], acc, 0, 0, 0);
        }
        {
            const short8 af = *(const short8*)(smem + cb + cOfs);
            acc = __builtin_amdgcn_mfma_f32_16x16x32_bf16(af, bfrag[12], acc, 0, 0, 0);
        }

        // 5. epilogue: relu + max over d (rows), write out
        float mx = fmaxf(fmaxf(acc[0], acc[1]), fmaxf(acc[2], acc[3]));
        mx = fmaxf(mx, 0.0f);
        mx = fmaxf(mx, __shfl_xor(mx, 16, 64));   // pair row-quads within vertex
        if (((lane >> 4) & 1) == 0)
            out[(2 * p + (lane >> 5)) * kF + f] = mx;

        p = pn;
        ib ^= 1;
    }
}

extern "C" void kernel_launch(void* const* d_in, const int* in_sizes, int n_in,
                              void* d_out, int out_size, void* d_ws, size_t ws_size,
                              hipStream_t stream) {
    const float* y    = reinterpret_cast<const float*>(d_in[0]);
    const int*   sf   = reinterpret_cast<const int*>(d_in[1]);
    const float* kern = reinterpret_cast<const float*>(d_in[2]);
    const float* ck   = reinterpret_cast<const float*>(d_in[3]);
    const float* bias = reinterpret_cast<const float*>(d_in[4]);
    float* out = reinterpret_cast<float*>(d_out);

    sgc_kernel<<<NWAVES, 64, 0, stream>>>(y, sf, kern, ck, bias, out);
}